// Round 1
// baseline (949.032 us; speedup 1.0000x reference)
//
#include <hip/hip_runtime.h>
#include <math.h>

#define WAVE 64

static inline size_t align256(size_t x) { return (x + 255) & ~(size_t)255; }

// ---------- CSR build ----------
__global__ void count_cols(const int* __restrict__ col, int E, int* __restrict__ cnt) {
    int e = blockIdx.x * blockDim.x + threadIdx.x;
    if (e < E) atomicAdd(&cnt[col[e]], 1);
}

__global__ void compute_dinv(const int* __restrict__ cnt, float* __restrict__ dinv, int N) {
    int v = blockIdx.x * blockDim.x + threadIdx.x;
    if (v < N) dinv[v] = rsqrtf((float)(cnt[v] + 1));   // +1 self loop
}

__global__ void scan_offsets(const int* __restrict__ cnt, int* __restrict__ offsets,
                             int* __restrict__ fillpos, int N) {
    __shared__ int partial[256];
    __shared__ int base[257];
    int t = threadIdx.x;
    int chunk = (N + 255) / 256;
    int start = t * chunk;
    int end = min(start + chunk, N);
    int s = 0;
    for (int i = start; i < end; i++) s += cnt[i];
    partial[t] = s;
    __syncthreads();
    if (t == 0) {
        int acc = 0;
        for (int i = 0; i < 256; i++) { base[i] = acc; acc += partial[i]; }
        base[256] = acc;
    }
    __syncthreads();
    int acc = base[t];
    for (int i = start; i < end; i++) {
        offsets[i] = acc;
        fillpos[i] = acc;
        acc += cnt[i];
    }
    if (t == 255) offsets[N] = base[256];
}

__global__ void fill_csr(const int* __restrict__ row, const int* __restrict__ col, int E,
                         int* __restrict__ fillpos, int* __restrict__ csr_src) {
    int e = blockIdx.x * blockDim.x + threadIdx.x;
    if (e < E) {
        int p = atomicAdd(&fillpos[col[e]], 1);
        csr_src[p] = row[e];
    }
}

// ---------- f32 tiled GEMM: C[M x Nc] = A[M x K] @ B[K x Nc] ----------
template<int BM, int BN, int BK, int TM, int TN>
__global__ __launch_bounds__(256) void gemm_f32(const float* __restrict__ A,
                                                const float* __restrict__ B,
                                                float* __restrict__ C,
                                                int M, int Nc, int K) {
    __shared__ float As[BK][BM + 1];
    __shared__ float Bs[BK][BN + 1];
    int tid = threadIdx.x;
    int tx = tid % (BN / TN);
    int ty = tid / (BN / TN);
    int brow = blockIdx.y * BM;
    int bcol = blockIdx.x * BN;
    float acc[TM][TN];
    for (int m = 0; m < TM; m++)
        for (int n = 0; n < TN; n++) acc[m][n] = 0.f;
    for (int k0 = 0; k0 < K; k0 += BK) {
        for (int i = tid; i < BM * BK; i += 256) {
            int r = i / BK, c = i % BK;
            As[c][r] = A[(size_t)(brow + r) * K + k0 + c];
        }
        for (int i = tid; i < BK * BN; i += 256) {
            int r = i / BN, c = i % BN;
            Bs[r][c] = B[(size_t)(k0 + r) * Nc + bcol + c];
        }
        __syncthreads();
        #pragma unroll
        for (int k = 0; k < BK; k++) {
            float a[TM], b[TN];
            #pragma unroll
            for (int m = 0; m < TM; m++) a[m] = As[k][ty * TM + m];
            #pragma unroll
            for (int n = 0; n < TN; n++) b[n] = Bs[k][tx * TN + n];
            #pragma unroll
            for (int m = 0; m < TM; m++)
                #pragma unroll
                for (int n = 0; n < TN; n++) acc[m][n] += a[m] * b[n];
        }
        __syncthreads();
    }
    for (int m = 0; m < TM; m++)
        for (int n = 0; n < TN; n++)
            C[(size_t)(brow + ty * TM + m) * Nc + bcol + tx * TN + n] = acc[m][n];
}

// ---------- GCN aggregation (gather, one wave per node), H == 256 ----------
__global__ __launch_bounds__(256) void gcn_aggregate(const float* __restrict__ xw,
                                                     const float* __restrict__ dinv,
                                                     const int* __restrict__ offsets,
                                                     const int* __restrict__ csr_src,
                                                     const float* __restrict__ bias,
                                                     float* __restrict__ out,
                                                     int N, int H, int relu_flag) {
    int gw = (blockIdx.x * blockDim.x + threadIdx.x) >> 6;
    int lane = threadIdx.x & (WAVE - 1);
    if (gw >= N) return;
    int v = gw;
    float dv = dinv[v];
    const float4* xv = (const float4*)(xw + (size_t)v * H);
    float4 acc = xv[lane];
    float s = dv * dv;
    acc.x *= s; acc.y *= s; acc.z *= s; acc.w *= s;
    int beg = offsets[v], end = offsets[v + 1];
    for (int e = beg; e < end; e++) {
        int r = csr_src[e];
        float nrm = dinv[r] * dv;
        float4 xr = ((const float4*)(xw + (size_t)r * H))[lane];
        acc.x += nrm * xr.x; acc.y += nrm * xr.y;
        acc.z += nrm * xr.z; acc.w += nrm * xr.w;
    }
    float4 bb = ((const float4*)bias)[lane];
    acc.x += bb.x; acc.y += bb.y; acc.z += bb.z; acc.w += bb.w;
    if (relu_flag) {
        acc.x = fmaxf(acc.x, 0.f); acc.y = fmaxf(acc.y, 0.f);
        acc.z = fmaxf(acc.z, 0.f); acc.w = fmaxf(acc.w, 0.f);
    }
    ((float4*)(out + (size_t)v * H))[lane] = acc;
}

// ---------- double L2 norm in place, one wave per row, H == 256 ----------
__global__ __launch_bounds__(256) void l2norm_twice(float* __restrict__ rep, int N, int H) {
    int gw = (blockIdx.x * blockDim.x + threadIdx.x) >> 6;
    int lane = threadIdx.x & (WAVE - 1);
    if (gw >= N) return;
    float4* p = (float4*)(rep + (size_t)gw * H);
    float4 v = p[lane];
    float ss = v.x * v.x + v.y * v.y + v.z * v.z + v.w * v.w;
    #pragma unroll
    for (int o = 1; o < WAVE; o <<= 1) ss += __shfl_xor(ss, o);
    float n1 = fmaxf(sqrtf(ss), 1e-12f);
    float i1 = 1.f / n1;
    float n2 = fmaxf(sqrtf(ss) * i1, 1e-12f);   // norm of normalized vector
    float sc = i1 / n2;
    v.x *= sc; v.y *= sc; v.z *= sc; v.w *= sc;
    p[lane] = v;
}

// ---------- y = rep @ Wy + by ----------
__global__ void linear_y(const float* __restrict__ rep, const float* __restrict__ Wy,
                         const float* __restrict__ by, float* __restrict__ y,
                         int N, int H, int C) {
    long t = blockIdx.x * (long)blockDim.x + threadIdx.x;
    if (t >= (long)N * C) return;
    int i = (int)(t / C), j = (int)(t % C);
    float acc = by[j];
    for (int k = 0; k < H; k++) acc += rep[(size_t)i * H + k] * Wy[(size_t)k * C + j];
    y[t] = acc;
}

// ---------- loss over positive + negative edges ----------
__global__ __launch_bounds__(256) void loss_edges(const float* __restrict__ rep,
                                                  const int* __restrict__ pos_e,
                                                  const int* __restrict__ neg_e,
                                                  const float* __restrict__ sim,
                                                  const float* __restrict__ lsm,
                                                  float* __restrict__ accum,
                                                  int E, int N, int H) {
    int gw = (blockIdx.x * blockDim.x + threadIdx.x) >> 6;
    int lane = threadIdx.x & (WAVE - 1);
    int nw = (gridDim.x * blockDim.x) >> 6;
    float tgt = lsm[0];
    float sse = 0.f, cnt = 0.f;
    for (int e = gw; e < 2 * E; e += nw) {
        bool is_pos = e < E;
        int idx = is_pos ? e : e - E;
        const int* ei = is_pos ? pos_e : neg_e;
        int a = ei[idx];
        int b = ei[E + idx];
        if (a < b) {
            const float4* ra = (const float4*)(rep + (size_t)a * H);
            const float4* rb = (const float4*)(rep + (size_t)b * H);
            float4 va = ra[lane], vb = rb[lane];
            float d = va.x * vb.x + va.y * vb.y + va.z * vb.z + va.w * vb.w;
            #pragma unroll
            for (int o = 1; o < WAVE; o <<= 1) d += __shfl_xor(d, o);
            float w = fmaxf(d, 0.f);
            float term;
            if (is_pos) {
                float fsim = sim[(size_t)a * N + b];
                float pos = fsim * 0.5f + w * 0.5f;
                term = (pos - tgt) * (pos - tgt);
            } else {
                term = w * w;
            }
            sse += term;
            cnt += 1.f;
        }
    }
    if (lane == 0) {
        atomicAdd(&accum[0], sse);
        atomicAdd(&accum[1], cnt);
    }
}

__global__ void finalize_loss(const float* __restrict__ accum, float* __restrict__ out_loss, int n) {
    if (threadIdx.x == 0 && blockIdx.x == 0)
        out_loss[0] = accum[0] * (float)n / accum[1];
}

extern "C" void kernel_launch(void* const* d_in, const int* in_sizes, int n_in,
                              void* d_out, int out_size, void* d_ws, size_t ws_size,
                              hipStream_t stream) {
    const int*   edge = (const int*)d_in[0];
    const int*   nedge = (const int*)d_in[1];
    const float* feat = (const float*)d_in[2];
    const float* sim  = (const float*)d_in[3];
    const float* lsm  = (const float*)d_in[4];
    const float* W1   = (const float*)d_in[5];
    const float* b1   = (const float*)d_in[6];
    const float* W2   = (const float*)d_in[7];
    const float* b2   = (const float*)d_in[8];
    const float* Wy   = (const float*)d_in[9];
    const float* by   = (const float*)d_in[10];

    const int E = in_sizes[0] / 2;
    const int H = in_sizes[6];           // 256
    const int C = in_sizes[10];          // 40
    const int F = in_sizes[5] / H;       // 256
    const int N = in_sizes[2] / F;       // 16384

    const int* e_row = edge;             // edge_index[0]
    const int* e_col = edge + E;         // edge_index[1]

    // workspace carve-up
    char* p = (char*)d_ws;
    int*   cnt     = (int*)p;   p += align256((size_t)N * 4);
    float* dinv    = (float*)p; p += align256((size_t)N * 4);
    int*   offsets = (int*)p;   p += align256((size_t)(N + 1) * 4);
    int*   fillpos = (int*)p;   p += align256((size_t)N * 4);
    int*   csr_src = (int*)p;   p += align256((size_t)E * 4);
    float* xw      = (float*)p; p += align256((size_t)N * H * 4);
    float* h1      = (float*)p; p += align256((size_t)N * H * 4);
    float* accum   = (float*)p; p += 256;

    float* rep  = (float*)d_out;
    float* loss = rep + (size_t)N * H;
    float* yout = loss + 1;

    hipMemsetAsync(cnt, 0, (size_t)N * 4, stream);
    hipMemsetAsync(accum, 0, 2 * sizeof(float), stream);

    // CSR build
    count_cols<<<(E + 255) / 256, 256, 0, stream>>>(e_col, E, cnt);
    compute_dinv<<<(N + 255) / 256, 256, 0, stream>>>(cnt, dinv, N);
    scan_offsets<<<1, 256, 0, stream>>>(cnt, offsets, fillpos, N);
    fill_csr<<<(E + 255) / 256, 256, 0, stream>>>(e_row, e_col, E, fillpos, csr_src);

    dim3 gblk(256);
    // conv1: xw = feat @ W1 ; h1 = relu(agg(xw) + b1)
    {
        dim3 grid(H / 64, N / 64);
        gemm_f32<64, 64, 16, 4, 4><<<grid, gblk, 0, stream>>>(feat, W1, xw, N, H, F);
    }
    gcn_aggregate<<<N / 4, 256, 0, stream>>>(xw, dinv, offsets, csr_src, b1, h1, N, H, 1);

    // conv2: xw = h1 @ W2 ; rep_raw = agg(xw) + b2  (into d_out)
    {
        dim3 grid(H / 64, N / 64);
        gemm_f32<64, 64, 16, 4, 4><<<grid, gblk, 0, stream>>>(h1, W2, xw, N, H, H);
    }
    gcn_aggregate<<<N / 4, 256, 0, stream>>>(xw, dinv, offsets, csr_src, b2, rep, N, H, 0);

    // rep = l2norm(l2norm(rep_raw))
    l2norm_twice<<<N / 4, 256, 0, stream>>>(rep, N, H);

    // y = rep @ Wy + by
    linear_y<<<(int)(((long)N * C + 255) / 256), 256, 0, stream>>>(rep, Wy, by, yout, N, H, C);

    // reconstruction loss
    loss_edges<<<4096, 256, 0, stream>>>(rep, edge, nedge, sim, lsm, accum, E, N, H);
    finalize_loss<<<1, 64, 0, stream>>>(accum, loss, N);
}

// Round 2
// 847.542 us; speedup vs baseline: 1.1197x; 1.1197x over previous
//
#include <hip/hip_runtime.h>
#include <math.h>

#define WAVE 64

typedef __attribute__((ext_vector_type(8))) short bf16x8;
typedef __attribute__((ext_vector_type(4))) float f32x4;

static inline size_t align256(size_t x) { return (x + 255) & ~(size_t)255; }

__device__ inline ushort f2bf(float f) {
    uint u = __float_as_uint(f);
    u = (u + 0x7fffu + ((u >> 16) & 1u)) >> 16;
    return (ushort)u;
}
__device__ inline float bf2f(ushort b) { return __uint_as_float(((uint)b) << 16); }

// ---------- CSR build ----------
__global__ void count_cols(const int* __restrict__ col, int E, int* __restrict__ cnt) {
    int e = blockIdx.x * blockDim.x + threadIdx.x;
    if (e < E) atomicAdd(&cnt[col[e]], 1);
}

__global__ void compute_dinv(const int* __restrict__ cnt, float* __restrict__ dinv, int N) {
    int v = blockIdx.x * blockDim.x + threadIdx.x;
    if (v < N) dinv[v] = rsqrtf((float)(cnt[v] + 1));   // +1 self loop
}

__global__ void scan_offsets(const int* __restrict__ cnt, int* __restrict__ offsets,
                             int* __restrict__ fillpos, int N) {
    __shared__ int partial[256];
    __shared__ int base[257];
    int t = threadIdx.x;
    int chunk = (N + 255) / 256;
    int start = t * chunk;
    int end = min(start + chunk, N);
    int s = 0;
    for (int i = start; i < end; i++) s += cnt[i];
    partial[t] = s;
    __syncthreads();
    if (t == 0) {
        int acc = 0;
        for (int i = 0; i < 256; i++) { base[i] = acc; acc += partial[i]; }
        base[256] = acc;
    }
    __syncthreads();
    int acc = base[t];
    for (int i = start; i < end; i++) {
        offsets[i] = acc;
        fillpos[i] = acc;
        acc += cnt[i];
    }
    if (t == 255) offsets[N] = base[256];
}

__global__ void fill_csr(const int* __restrict__ row, const int* __restrict__ col, int E,
                         int* __restrict__ fillpos, int* __restrict__ csr_src) {
    int e = blockIdx.x * blockDim.x + threadIdx.x;
    if (e < E) {
        int p = atomicAdd(&fillpos[col[e]], 1);
        csr_src[p] = row[e];
    }
}

// ---------- f32 -> bf16 elementwise (n8 = count/8) ----------
__global__ void f32_to_bf16_kernel(const float* __restrict__ in, ushort* __restrict__ out, long n8) {
    long i = blockIdx.x * (long)blockDim.x + threadIdx.x;
    if (i >= n8) return;
    const float4* p = (const float4*)(in + i * 8);
    float4 a = p[0], b = p[1];
    union { ushort us[8]; uint4 v; } u;
    u.us[0] = f2bf(a.x); u.us[1] = f2bf(a.y); u.us[2] = f2bf(a.z); u.us[3] = f2bf(a.w);
    u.us[4] = f2bf(b.x); u.us[5] = f2bf(b.y); u.us[6] = f2bf(b.z); u.us[7] = f2bf(b.w);
    *(uint4*)(out + i * 8) = u.v;
}

// ---------- W [K][Nn] f32 -> Wt [n][k] bf16 (transpose + convert) ----------
__global__ void convW_kernel(const float* __restrict__ W, ushort* __restrict__ Wt, int K, int Nn) {
    int idx = blockIdx.x * blockDim.x + threadIdx.x;
    if (idx >= K * Nn) return;
    int k = idx / Nn, n = idx % Nn;
    Wt[(size_t)n * K + k] = f2bf(W[idx]);
}

// ---------- bf16 MFMA GEMM: C[M x 256] = A[M x 256] @ Bt^T, all bf16, C bf16 ----------
// A row-major [M][256]; Bt row-major [n][k] (i.e. B transposed); C row-major [M][256].
__global__ __launch_bounds__(256) void gemm_bf16_kernel(const ushort* __restrict__ A,
                                                        const ushort* __restrict__ Bt,
                                                        ushort* __restrict__ C, int M) {
    __shared__ ushort As[128][40];   // 32 k padded to 40 (80B rows, conflict-free-ish)
    __shared__ ushort Bs[128][40];
    const int K = 256;
    int t = threadIdx.x;
    int lane = t & 63, w = t >> 6;
    int wm = w >> 1, wn = w & 1;
    int brow = blockIdx.y * 128, bcol = blockIdx.x * 128;
    int l15 = lane & 15, l4 = lane >> 4;

    f32x4 acc[4][4];
    for (int i = 0; i < 4; i++)
        for (int j = 0; j < 4; j++) {
            f32x4 z = {0.f, 0.f, 0.f, 0.f};
            acc[i][j] = z;
        }

    for (int k0 = 0; k0 < K; k0 += 32) {
        // stage 128x32 bf16 tiles of A and Bt (8 KB each)
        #pragma unroll
        for (int i = 0; i < 2; i++) {
            int idx = t + i * 256;
            int r = idx >> 2, seg = idx & 3;
            uint4 va = *(const uint4*)(A  + (size_t)(brow + r) * K + k0 + seg * 8);
            uint4 vb = *(const uint4*)(Bt + (size_t)(bcol + r) * K + k0 + seg * 8);
            *(uint4*)&As[r][seg * 8] = va;
            *(uint4*)&Bs[r][seg * 8] = vb;
        }
        __syncthreads();

        bf16x8 af[4], bf[4];
        #pragma unroll
        for (int mf = 0; mf < 4; mf++)
            af[mf] = *(const bf16x8*)&As[wm * 64 + mf * 16 + l15][l4 * 8];
        #pragma unroll
        for (int nf = 0; nf < 4; nf++)
            bf[nf] = *(const bf16x8*)&Bs[wn * 64 + nf * 16 + l15][l4 * 8];

        #pragma unroll
        for (int mf = 0; mf < 4; mf++)
            #pragma unroll
            for (int nf = 0; nf < 4; nf++)
                acc[mf][nf] = __builtin_amdgcn_mfma_f32_16x16x32_bf16(af[mf], bf[nf], acc[mf][nf], 0, 0, 0);
        __syncthreads();
    }

    // epilogue: C/D layout col = lane&15, row = (lane>>4)*4 + j
    #pragma unroll
    for (int mf = 0; mf < 4; mf++)
        #pragma unroll
        for (int nf = 0; nf < 4; nf++)
            #pragma unroll
            for (int j = 0; j < 4; j++) {
                int r = brow + wm * 64 + mf * 16 + l4 * 4 + j;
                int c = bcol + wn * 64 + nf * 16 + l15;
                C[(size_t)r * 256 + c] = f2bf(acc[mf][nf][j]);
            }
}

// ---------- GCN aggregation pass1 (bf16 in, relu, bf16 out), one wave/node ----------
__global__ __launch_bounds__(256) void gcn_agg1_kernel(const ushort* __restrict__ xw,
                                                       const float* __restrict__ dinv,
                                                       const int* __restrict__ offsets,
                                                       const int* __restrict__ csr_src,
                                                       const float* __restrict__ bias,
                                                       ushort* __restrict__ out_b, int N) {
    int gw = (blockIdx.x * blockDim.x + threadIdx.x) >> 6;
    int lane = threadIdx.x & 63;
    if (gw >= N) return;
    float dv = dinv[gw];
    float s = dv * dv;
    ushort4 q = *(const ushort4*)(xw + (size_t)gw * 256 + lane * 4);
    float ax = bf2f(q.x) * s, ay = bf2f(q.y) * s, az = bf2f(q.z) * s, aw = bf2f(q.w) * s;
    int beg = offsets[gw], end = offsets[gw + 1];
    for (int e = beg; e < end; e++) {
        int r = csr_src[e];
        float nrm = dinv[r] * dv;
        ushort4 p = *(const ushort4*)(xw + (size_t)r * 256 + lane * 4);
        ax += nrm * bf2f(p.x); ay += nrm * bf2f(p.y);
        az += nrm * bf2f(p.z); aw += nrm * bf2f(p.w);
    }
    float4 bb = ((const float4*)bias)[lane];
    ax = fmaxf(ax + bb.x, 0.f); ay = fmaxf(ay + bb.y, 0.f);
    az = fmaxf(az + bb.z, 0.f); aw = fmaxf(aw + bb.w, 0.f);
    ushort4 o;
    o.x = f2bf(ax); o.y = f2bf(ay); o.z = f2bf(az); o.w = f2bf(aw);
    *(ushort4*)(out_b + (size_t)gw * 256 + lane * 4) = o;
}

// ---------- fused: agg pass2 + bias + double l2norm + rep/repb write + y = rep@Wy+by ----------
__global__ __launch_bounds__(256) void gcn_agg2_fused_kernel(const ushort* __restrict__ xw,
                                                             const float* __restrict__ dinv,
                                                             const int* __restrict__ offsets,
                                                             const int* __restrict__ csr_src,
                                                             const float* __restrict__ b2,
                                                             const float* __restrict__ Wy,
                                                             const float* __restrict__ by,
                                                             float* __restrict__ rep,
                                                             ushort* __restrict__ repb,
                                                             float* __restrict__ y, int N) {
    __shared__ float WyT[40 * 256];     // 40 KB, [j][k]
    int t = threadIdx.x;
    for (int i = t; i < 40 * 256; i += 256) {
        int j = i >> 8, k = i & 255;
        WyT[i] = Wy[(size_t)k * 40 + j];
    }
    __syncthreads();

    int lane = t & 63;
    int wid = (blockIdx.x * 256 + t) >> 6;
    int nw = (gridDim.x * 256) >> 6;
    for (int v = wid; v < N; v += nw) {
        float dv = dinv[v];
        float s = dv * dv;
        ushort4 q = *(const ushort4*)(xw + (size_t)v * 256 + lane * 4);
        float ax = bf2f(q.x) * s, ay = bf2f(q.y) * s, az = bf2f(q.z) * s, aw = bf2f(q.w) * s;
        int beg = offsets[v], end = offsets[v + 1];
        for (int e = beg; e < end; e++) {
            int r = csr_src[e];
            float nrm = dinv[r] * dv;
            ushort4 p = *(const ushort4*)(xw + (size_t)r * 256 + lane * 4);
            ax += nrm * bf2f(p.x); ay += nrm * bf2f(p.y);
            az += nrm * bf2f(p.z); aw += nrm * bf2f(p.w);
        }
        float4 bb = ((const float4*)b2)[lane];
        ax += bb.x; ay += bb.y; az += bb.z; aw += bb.w;

        float ss = ax * ax + ay * ay + az * az + aw * aw;
        #pragma unroll
        for (int o = 1; o < WAVE; o <<= 1) ss += __shfl_xor(ss, o);
        float n1 = fmaxf(sqrtf(ss), 1e-12f);
        float i1 = 1.f / n1;
        float n2 = fmaxf(sqrtf(ss) * i1, 1e-12f);
        float sc = i1 / n2;
        ax *= sc; ay *= sc; az *= sc; aw *= sc;

        float4 ov; ov.x = ax; ov.y = ay; ov.z = az; ov.w = aw;
        *(float4*)(rep + (size_t)v * 256 + lane * 4) = ov;
        ushort4 ob; ob.x = f2bf(ax); ob.y = f2bf(ay); ob.z = f2bf(az); ob.w = f2bf(aw);
        *(ushort4*)(repb + (size_t)v * 256 + lane * 4) = ob;

        float myy = 0.f;
        for (int j = 0; j < 40; j++) {
            const float4 wv = *(const float4*)&WyT[j * 256 + lane * 4];
            float d = ax * wv.x + ay * wv.y + az * wv.z + aw * wv.w;
            #pragma unroll
            for (int o = 1; o < WAVE; o <<= 1) d += __shfl_xor(d, o);
            if (lane == j) myy = d;
        }
        if (lane < 40) y[(size_t)v * 40 + lane] = myy + by[lane];
    }
}

// ---------- loss over positive + negative edges (bf16 rep) ----------
__global__ __launch_bounds__(256) void loss_edges_kernel(const ushort* __restrict__ repb,
                                                         const int* __restrict__ pos_e,
                                                         const int* __restrict__ neg_e,
                                                         const float* __restrict__ sim,
                                                         const float* __restrict__ lsm,
                                                         float* __restrict__ accum,
                                                         int E, int N) {
    int gw = (blockIdx.x * blockDim.x + threadIdx.x) >> 6;
    int lane = threadIdx.x & 63;
    int nw = (gridDim.x * blockDim.x) >> 6;
    float tgt = lsm[0];
    float sse = 0.f, cnt = 0.f;
    for (int e = gw; e < 2 * E; e += nw) {
        bool is_pos = e < E;
        int idx = is_pos ? e : e - E;
        const int* ei = is_pos ? pos_e : neg_e;
        int a = ei[idx];
        int b = ei[E + idx];
        if (a < b) {
            ushort4 qa = *(const ushort4*)(repb + (size_t)a * 256 + lane * 4);
            ushort4 qb = *(const ushort4*)(repb + (size_t)b * 256 + lane * 4);
            float d = bf2f(qa.x) * bf2f(qb.x) + bf2f(qa.y) * bf2f(qb.y)
                    + bf2f(qa.z) * bf2f(qb.z) + bf2f(qa.w) * bf2f(qb.w);
            #pragma unroll
            for (int o = 1; o < WAVE; o <<= 1) d += __shfl_xor(d, o);
            float wr = fmaxf(d, 0.f);
            float term;
            if (is_pos) {
                float fsim = sim[(size_t)a * N + b];
                float p = fsim * 0.5f + wr * 0.5f;
                term = (p - tgt) * (p - tgt);
            } else {
                term = wr * wr;
            }
            sse += term;
            cnt += 1.f;
        }
    }
    if (lane == 0) {
        atomicAdd(&accum[0], sse);
        atomicAdd(&accum[1], cnt);
    }
}

__global__ void finalize_loss(const float* __restrict__ accum, float* __restrict__ out_loss, int n) {
    if (threadIdx.x == 0 && blockIdx.x == 0)
        out_loss[0] = accum[0] * (float)n / accum[1];
}

extern "C" void kernel_launch(void* const* d_in, const int* in_sizes, int n_in,
                              void* d_out, int out_size, void* d_ws, size_t ws_size,
                              hipStream_t stream) {
    const int*   edge  = (const int*)d_in[0];
    const int*   nedge = (const int*)d_in[1];
    const float* feat  = (const float*)d_in[2];
    const float* sim   = (const float*)d_in[3];
    const float* lsm   = (const float*)d_in[4];
    const float* W1    = (const float*)d_in[5];
    const float* b1    = (const float*)d_in[6];
    const float* W2    = (const float*)d_in[7];
    const float* b2    = (const float*)d_in[8];
    const float* Wy    = (const float*)d_in[9];
    const float* by    = (const float*)d_in[10];

    const int E = in_sizes[0] / 2;
    const int H = in_sizes[6];           // 256
    const int F = in_sizes[5] / H;       // 256
    const int N = in_sizes[2] / F;       // 16384

    const int* e_row = edge;
    const int* e_col = edge + E;

    // workspace carve-up
    char* p = (char*)d_ws;
    int*    cnt     = (int*)p;    p += align256((size_t)N * 4);
    float*  dinv    = (float*)p;  p += align256((size_t)N * 4);
    int*    offsets = (int*)p;    p += align256((size_t)(N + 1) * 4);
    int*    fillpos = (int*)p;    p += align256((size_t)N * 4);
    int*    csr_src = (int*)p;    p += align256((size_t)E * 4);
    ushort* W1t     = (ushort*)p; p += align256((size_t)F * H * 2);
    ushort* W2t     = (ushort*)p; p += align256((size_t)H * H * 2);
    ushort* featb   = (ushort*)p; p += align256((size_t)N * F * 2);
    ushort* h1b     = (ushort*)p; p += align256((size_t)N * H * 2);
    ushort* xwb     = (ushort*)p; p += align256((size_t)N * H * 2);
    ushort* repb    = (ushort*)p; p += align256((size_t)N * H * 2);
    float*  accum   = (float*)p;  p += 256;

    float* rep  = (float*)d_out;
    float* loss = rep + (size_t)N * H;
    float* yout = loss + 1;

    hipMemsetAsync(cnt, 0, (size_t)N * 4, stream);
    hipMemsetAsync(accum, 0, 2 * sizeof(float), stream);

    // CSR build
    count_cols<<<(E + 255) / 256, 256, 0, stream>>>(e_col, E, cnt);
    compute_dinv<<<(N + 255) / 256, 256, 0, stream>>>(cnt, dinv, N);
    scan_offsets<<<1, 256, 0, stream>>>(cnt, offsets, fillpos, N);
    fill_csr<<<(E + 255) / 256, 256, 0, stream>>>(e_row, e_col, E, fillpos, csr_src);

    // conversions
    f32_to_bf16_kernel<<<(int)(((long)N * F / 8 + 255) / 256), 256, 0, stream>>>(feat, featb, (long)N * F / 8);
    convW_kernel<<<(F * H + 255) / 256, 256, 0, stream>>>(W1, W1t, F, H);
    convW_kernel<<<(H * H + 255) / 256, 256, 0, stream>>>(W2, W2t, H, H);

    // conv1: xwb = featb @ W1 (bf16 MFMA), h1b = bf16(relu(agg(xwb)+b1))
    {
        dim3 grid(2, N / 128);
        gemm_bf16_kernel<<<grid, 256, 0, stream>>>(featb, W1t, xwb, N);
    }
    gcn_agg1_kernel<<<N / 4, 256, 0, stream>>>(xwb, dinv, offsets, csr_src, b1, h1b, N);

    // conv2: xwb = h1b @ W2; fused agg2 + l2norm^2 + y
    {
        dim3 grid(2, N / 128);
        gemm_bf16_kernel<<<grid, 256, 0, stream>>>(h1b, W2t, xwb, N);
    }
    gcn_agg2_fused_kernel<<<2048, 256, 0, stream>>>(xwb, dinv, offsets, csr_src, b2, Wy, by,
                                                    rep, repb, yout, N);

    // reconstruction loss
    loss_edges_kernel<<<4096, 256, 0, stream>>>(repb, edge, nedge, sim, lsm, accum, E, N);
    finalize_loss<<<1, 64, 0, stream>>>(accum, loss, N);
}

// Round 3
// 490.408 us; speedup vs baseline: 1.9352x; 1.7282x over previous
//
#include <hip/hip_runtime.h>
#include <math.h>

#define WAVE 64

typedef __attribute__((ext_vector_type(8))) short bf16x8;
typedef __attribute__((ext_vector_type(4))) float f32x4;

static inline size_t align256(size_t x) { return (x + 255) & ~(size_t)255; }

__device__ inline ushort f2bf(float f) {
    uint u = __float_as_uint(f);
    u = (u + 0x7fffu + ((u >> 16) & 1u)) >> 16;
    return (ushort)u;
}
__device__ inline float bf2f(ushort b) { return __uint_as_float(((uint)b) << 16); }

// ---------- CSR build ----------
__global__ void count_cols(const int* __restrict__ col, int E, int* __restrict__ cnt) {
    int e = blockIdx.x * blockDim.x + threadIdx.x;
    if (e < E) atomicAdd(&cnt[col[e]], 1);
}

__global__ void compute_dinv(const int* __restrict__ cnt, float* __restrict__ dinv, int N) {
    int v = blockIdx.x * blockDim.x + threadIdx.x;
    if (v < N) dinv[v] = rsqrtf((float)(cnt[v] + 1));   // +1 self loop
}

__global__ void scan_offsets(const int* __restrict__ cnt, int* __restrict__ offsets,
                             int* __restrict__ fillpos, int N) {
    __shared__ int partial[256];
    __shared__ int base[257];
    int t = threadIdx.x;
    int chunk = (N + 255) / 256;
    int start = t * chunk;
    int end = min(start + chunk, N);
    int s = 0;
    for (int i = start; i < end; i++) s += cnt[i];
    partial[t] = s;
    __syncthreads();
    if (t == 0) {
        int acc = 0;
        for (int i = 0; i < 256; i++) { base[i] = acc; acc += partial[i]; }
        base[256] = acc;
    }
    __syncthreads();
    int acc = base[t];
    for (int i = start; i < end; i++) {
        offsets[i] = acc;
        fillpos[i] = acc;
        acc += cnt[i];
    }
    if (t == 255) offsets[N] = base[256];
}

__global__ void fill_csr(const int* __restrict__ row, const int* __restrict__ col, int E,
                         int* __restrict__ fillpos, int* __restrict__ csr_src) {
    int e = blockIdx.x * blockDim.x + threadIdx.x;
    if (e < E) {
        int p = atomicAdd(&fillpos[col[e]], 1);
        csr_src[p] = row[e];
    }
}

// ---------- f32 -> bf16 elementwise (n8 = count/8) ----------
__global__ void f32_to_bf16_kernel(const float* __restrict__ in, ushort* __restrict__ out, long n8) {
    long i = blockIdx.x * (long)blockDim.x + threadIdx.x;
    if (i >= n8) return;
    const float4* p = (const float4*)(in + i * 8);
    float4 a = p[0], b = p[1];
    union { ushort us[8]; uint4 v; } u;
    u.us[0] = f2bf(a.x); u.us[1] = f2bf(a.y); u.us[2] = f2bf(a.z); u.us[3] = f2bf(a.w);
    u.us[4] = f2bf(b.x); u.us[5] = f2bf(b.y); u.us[6] = f2bf(b.z); u.us[7] = f2bf(b.w);
    *(uint4*)(out + i * 8) = u.v;
}

// ---------- W [K][Nn] f32 -> Wt [n][k] bf16 (transpose + convert) ----------
__global__ void convW_kernel(const float* __restrict__ W, ushort* __restrict__ Wt, int K, int Nn) {
    int idx = blockIdx.x * blockDim.x + threadIdx.x;
    if (idx >= K * Nn) return;
    int k = idx / Nn, n = idx % Nn;
    Wt[(size_t)n * K + k] = f2bf(W[idx]);
}

// ---------- bf16 MFMA GEMM: C[M x 256] = A[M x 256] @ Bt^T, all bf16, C bf16 ----------
__global__ __launch_bounds__(256) void gemm_bf16_kernel(const ushort* __restrict__ A,
                                                        const ushort* __restrict__ Bt,
                                                        ushort* __restrict__ C, int M) {
    __shared__ ushort As[128][40];
    __shared__ ushort Bs[128][40];
    const int K = 256;
    int t = threadIdx.x;
    int lane = t & 63, w = t >> 6;
    int wm = w >> 1, wn = w & 1;
    int brow = blockIdx.y * 128, bcol = blockIdx.x * 128;
    int l15 = lane & 15, l4 = lane >> 4;

    f32x4 acc[4][4];
    for (int i = 0; i < 4; i++)
        for (int j = 0; j < 4; j++) {
            f32x4 z = {0.f, 0.f, 0.f, 0.f};
            acc[i][j] = z;
        }

    for (int k0 = 0; k0 < K; k0 += 32) {
        #pragma unroll
        for (int i = 0; i < 2; i++) {
            int idx = t + i * 256;
            int r = idx >> 2, seg = idx & 3;
            uint4 va = *(const uint4*)(A  + (size_t)(brow + r) * K + k0 + seg * 8);
            uint4 vb = *(const uint4*)(Bt + (size_t)(bcol + r) * K + k0 + seg * 8);
            *(uint4*)&As[r][seg * 8] = va;
            *(uint4*)&Bs[r][seg * 8] = vb;
        }
        __syncthreads();

        bf16x8 af[4], bfr[4];
        #pragma unroll
        for (int mf = 0; mf < 4; mf++)
            af[mf] = *(const bf16x8*)&As[wm * 64 + mf * 16 + l15][l4 * 8];
        #pragma unroll
        for (int nf = 0; nf < 4; nf++)
            bfr[nf] = *(const bf16x8*)&Bs[wn * 64 + nf * 16 + l15][l4 * 8];

        #pragma unroll
        for (int mf = 0; mf < 4; mf++)
            #pragma unroll
            for (int nf = 0; nf < 4; nf++)
                acc[mf][nf] = __builtin_amdgcn_mfma_f32_16x16x32_bf16(af[mf], bfr[nf], acc[mf][nf], 0, 0, 0);
        __syncthreads();
    }

    #pragma unroll
    for (int mf = 0; mf < 4; mf++)
        #pragma unroll
        for (int nf = 0; nf < 4; nf++)
            #pragma unroll
            for (int j = 0; j < 4; j++) {
                int r = brow + wm * 64 + mf * 16 + l4 * 4 + j;
                int c = bcol + wn * 64 + nf * 16 + l15;
                C[(size_t)r * 256 + c] = f2bf(acc[mf][nf][j]);
            }
}

// ---------- GCN aggregation pass1 (bf16 in, relu, bf16 out), one wave/node ----------
__global__ __launch_bounds__(256) void gcn_agg1_kernel(const ushort* __restrict__ xw,
                                                       const float* __restrict__ dinv,
                                                       const int* __restrict__ offsets,
                                                       const int* __restrict__ csr_src,
                                                       const float* __restrict__ bias,
                                                       ushort* __restrict__ out_b, int N) {
    int gw = (blockIdx.x * blockDim.x + threadIdx.x) >> 6;
    int lane = threadIdx.x & 63;
    if (gw >= N) return;
    float dv = dinv[gw];
    float s = dv * dv;
    ushort4 q = *(const ushort4*)(xw + (size_t)gw * 256 + lane * 4);
    float ax = bf2f(q.x) * s, ay = bf2f(q.y) * s, az = bf2f(q.z) * s, aw = bf2f(q.w) * s;
    int beg = offsets[gw], end = offsets[gw + 1];
    for (int e = beg; e < end; e++) {
        int r = csr_src[e];
        float nrm = dinv[r] * dv;
        ushort4 p = *(const ushort4*)(xw + (size_t)r * 256 + lane * 4);
        ax += nrm * bf2f(p.x); ay += nrm * bf2f(p.y);
        az += nrm * bf2f(p.z); aw += nrm * bf2f(p.w);
    }
    float4 bb = ((const float4*)bias)[lane];
    ax = fmaxf(ax + bb.x, 0.f); ay = fmaxf(ay + bb.y, 0.f);
    az = fmaxf(az + bb.z, 0.f); aw = fmaxf(aw + bb.w, 0.f);
    ushort4 o;
    o.x = f2bf(ax); o.y = f2bf(ay); o.z = f2bf(az); o.w = f2bf(aw);
    *(ushort4*)(out_b + (size_t)gw * 256 + lane * 4) = o;
}

// ---------- fused: agg pass2 + bias + double l2norm + rep/repb write + y = rep@Wy+by ----------
__global__ __launch_bounds__(256) void gcn_agg2_fused_kernel(const ushort* __restrict__ xw,
                                                             const float* __restrict__ dinv,
                                                             const int* __restrict__ offsets,
                                                             const int* __restrict__ csr_src,
                                                             const float* __restrict__ b2,
                                                             const float* __restrict__ Wy,
                                                             const float* __restrict__ by,
                                                             float* __restrict__ rep,
                                                             ushort* __restrict__ repb,
                                                             float* __restrict__ y, int N) {
    __shared__ float WyT[40 * 256];     // [j][k], 40 KB
    int t = threadIdx.x;
    // coalesced global read, transposed LDS write
    for (int i = t; i < 40 * 256; i += 256) {
        int k = i / 40, j = i - k * 40;          // Wy is [k][j] row-major
        WyT[j * 256 + k] = Wy[i];
    }
    __syncthreads();

    int lane = t & 63;
    int wid = (blockIdx.x * 256 + t) >> 6;
    int nw = (gridDim.x * 256) >> 6;
    for (int v = wid; v < N; v += nw) {
        float dv = dinv[v];
        float s = dv * dv;
        ushort4 q = *(const ushort4*)(xw + (size_t)v * 256 + lane * 4);
        float ax = bf2f(q.x) * s, ay = bf2f(q.y) * s, az = bf2f(q.z) * s, aw = bf2f(q.w) * s;
        int beg = offsets[v], end = offsets[v + 1];
        for (int e = beg; e < end; e++) {
            int r = csr_src[e];
            float nrm = dinv[r] * dv;
            ushort4 p = *(const ushort4*)(xw + (size_t)r * 256 + lane * 4);
            ax += nrm * bf2f(p.x); ay += nrm * bf2f(p.y);
            az += nrm * bf2f(p.z); aw += nrm * bf2f(p.w);
        }
        float4 bb = ((const float4*)b2)[lane];
        ax += bb.x; ay += bb.y; az += bb.z; aw += bb.w;

        float ss = ax * ax + ay * ay + az * az + aw * aw;
        #pragma unroll
        for (int o = 1; o < WAVE; o <<= 1) ss += __shfl_xor(ss, o);
        float n1 = fmaxf(sqrtf(ss), 1e-12f);
        float i1 = 1.f / n1;
        float n2 = fmaxf(sqrtf(ss) * i1, 1e-12f);
        float sc = i1 / n2;
        ax *= sc; ay *= sc; az *= sc; aw *= sc;

        float4 ov; ov.x = ax; ov.y = ay; ov.z = az; ov.w = aw;
        *(float4*)(rep + (size_t)v * 256 + lane * 4) = ov;
        ushort4 ob; ob.x = f2bf(ax); ob.y = f2bf(ay); ob.z = f2bf(az); ob.w = f2bf(aw);
        *(ushort4*)(repb + (size_t)v * 256 + lane * 4) = ob;

        float myy = 0.f;
        for (int j = 0; j < 40; j++) {
            const float4 wv = *(const float4*)&WyT[j * 256 + lane * 4];
            float d = ax * wv.x + ay * wv.y + az * wv.z + aw * wv.w;
            #pragma unroll
            for (int o = 1; o < WAVE; o <<= 1) d += __shfl_xor(d, o);
            if (lane == j) myy = d;
        }
        if (lane < 40) y[(size_t)v * 40 + lane] = myy + by[lane];
    }
}

// ---------- loss over positive + negative edges (bf16 rep), NO contended atomics ----------
__global__ __launch_bounds__(256) void loss_edges_kernel(const ushort* __restrict__ repb,
                                                         const int* __restrict__ pos_e,
                                                         const int* __restrict__ neg_e,
                                                         const float* __restrict__ sim,
                                                         const float* __restrict__ lsm,
                                                         float2* __restrict__ partials,
                                                         int E, int N) {
    __shared__ float s_sse[4], s_cnt[4];
    int t = threadIdx.x;
    int gw = (blockIdx.x * blockDim.x + t) >> 6;
    int lane = t & 63;
    int w = t >> 6;
    int nw = (gridDim.x * blockDim.x) >> 6;
    float tgt = lsm[0];
    float sse = 0.f, cnt = 0.f;
    for (int e = gw; e < 2 * E; e += nw) {
        bool is_pos = e < E;
        int idx = is_pos ? e : e - E;
        const int* ei = is_pos ? pos_e : neg_e;
        int a = ei[idx];
        int b = ei[E + idx];
        if (a < b) {
            ushort4 qa = *(const ushort4*)(repb + (size_t)a * 256 + lane * 4);
            ushort4 qb = *(const ushort4*)(repb + (size_t)b * 256 + lane * 4);
            float d = bf2f(qa.x) * bf2f(qb.x) + bf2f(qa.y) * bf2f(qb.y)
                    + bf2f(qa.z) * bf2f(qb.z) + bf2f(qa.w) * bf2f(qb.w);
            #pragma unroll
            for (int o = 1; o < WAVE; o <<= 1) d += __shfl_xor(d, o);
            float wr = fmaxf(d, 0.f);
            float term;
            if (is_pos) {
                float fsim = sim[(size_t)a * N + b];
                float p = fsim * 0.5f + wr * 0.5f;
                term = (p - tgt) * (p - tgt);
            } else {
                term = wr * wr;
            }
            sse += term;
            cnt += 1.f;
        }
    }
    // all lanes hold identical sse/cnt (post-butterfly accumulation)
    if (lane == 0) { s_sse[w] = sse; s_cnt[w] = cnt; }
    __syncthreads();
    if (t == 0) {
        float2 p;
        p.x = s_sse[0] + s_sse[1] + s_sse[2] + s_sse[3];
        p.y = s_cnt[0] + s_cnt[1] + s_cnt[2] + s_cnt[3];
        partials[blockIdx.x] = p;
    }
}

__global__ __launch_bounds__(256) void finalize_loss_kernel(const float2* __restrict__ partials,
                                                            int nb, float* __restrict__ out_loss,
                                                            int n) {
    __shared__ float s_sse[4], s_cnt[4];
    int t = threadIdx.x;
    float sse = 0.f, cnt = 0.f;
    for (int i = t; i < nb; i += 256) {
        float2 p = partials[i];
        sse += p.x; cnt += p.y;
    }
    #pragma unroll
    for (int o = 1; o < WAVE; o <<= 1) { sse += __shfl_xor(sse, o); cnt += __shfl_xor(cnt, o); }
    int w = t >> 6;
    if ((t & 63) == 0) { s_sse[w] = sse; s_cnt[w] = cnt; }
    __syncthreads();
    if (t == 0) {
        float S = s_sse[0] + s_sse[1] + s_sse[2] + s_sse[3];
        float Cc = s_cnt[0] + s_cnt[1] + s_cnt[2] + s_cnt[3];
        out_loss[0] = S * (float)n / Cc;
    }
}

extern "C" void kernel_launch(void* const* d_in, const int* in_sizes, int n_in,
                              void* d_out, int out_size, void* d_ws, size_t ws_size,
                              hipStream_t stream) {
    const int*   edge  = (const int*)d_in[0];
    const int*   nedge = (const int*)d_in[1];
    const float* feat  = (const float*)d_in[2];
    const float* sim   = (const float*)d_in[3];
    const float* lsm   = (const float*)d_in[4];
    const float* W1    = (const float*)d_in[5];
    const float* b1    = (const float*)d_in[6];
    const float* W2    = (const float*)d_in[7];
    const float* b2    = (const float*)d_in[8];
    const float* Wy    = (const float*)d_in[9];
    const float* by    = (const float*)d_in[10];

    const int E = in_sizes[0] / 2;
    const int H = in_sizes[6];           // 256
    const int F = in_sizes[5] / H;       // 256
    const int N = in_sizes[2] / F;       // 16384

    const int* e_row = edge;
    const int* e_col = edge + E;

    const int LOSS_BLOCKS = 4096;

    // workspace carve-up
    char* p = (char*)d_ws;
    int*    cnt      = (int*)p;    p += align256((size_t)N * 4);
    float*  dinv     = (float*)p;  p += align256((size_t)N * 4);
    int*    offsets  = (int*)p;    p += align256((size_t)(N + 1) * 4);
    int*    fillpos  = (int*)p;    p += align256((size_t)N * 4);
    int*    csr_src  = (int*)p;    p += align256((size_t)E * 4);
    ushort* W1t      = (ushort*)p; p += align256((size_t)F * H * 2);
    ushort* W2t      = (ushort*)p; p += align256((size_t)H * H * 2);
    ushort* featb    = (ushort*)p; p += align256((size_t)N * F * 2);
    ushort* h1b      = (ushort*)p; p += align256((size_t)N * H * 2);
    ushort* xwb      = (ushort*)p; p += align256((size_t)N * H * 2);
    ushort* repb     = (ushort*)p; p += align256((size_t)N * H * 2);
    float2* partials = (float2*)p; p += align256((size_t)LOSS_BLOCKS * 8);

    float* rep  = (float*)d_out;
    float* loss = rep + (size_t)N * H;
    float* yout = loss + 1;

    hipMemsetAsync(cnt, 0, (size_t)N * 4, stream);

    // CSR build
    count_cols<<<(E + 255) / 256, 256, 0, stream>>>(e_col, E, cnt);
    compute_dinv<<<(N + 255) / 256, 256, 0, stream>>>(cnt, dinv, N);
    scan_offsets<<<1, 256, 0, stream>>>(cnt, offsets, fillpos, N);
    fill_csr<<<(E + 255) / 256, 256, 0, stream>>>(e_row, e_col, E, fillpos, csr_src);

    // conversions
    f32_to_bf16_kernel<<<(int)(((long)N * F / 8 + 255) / 256), 256, 0, stream>>>(feat, featb, (long)N * F / 8);
    convW_kernel<<<(F * H + 255) / 256, 256, 0, stream>>>(W1, W1t, F, H);
    convW_kernel<<<(H * H + 255) / 256, 256, 0, stream>>>(W2, W2t, H, H);

    // conv1
    {
        dim3 grid(2, N / 128);
        gemm_bf16_kernel<<<grid, 256, 0, stream>>>(featb, W1t, xwb, N);
    }
    gcn_agg1_kernel<<<N / 4, 256, 0, stream>>>(xwb, dinv, offsets, csr_src, b1, h1b, N);

    // conv2 + fused epilogue
    {
        dim3 grid(2, N / 128);
        gemm_bf16_kernel<<<grid, 256, 0, stream>>>(h1b, W2t, xwb, N);
    }
    gcn_agg2_fused_kernel<<<2048, 256, 0, stream>>>(xwb, dinv, offsets, csr_src, b2, Wy, by,
                                                    rep, repb, yout, N);

    // reconstruction loss (contention-free)
    loss_edges_kernel<<<LOSS_BLOCKS, 256, 0, stream>>>(repb, edge, nedge, sim, lsm, partials, E, N);
    finalize_loss_kernel<<<1, 256, 0, stream>>>(partials, LOSS_BLOCKS, loss, N);
}

// Round 4
// 408.612 us; speedup vs baseline: 2.3226x; 1.2002x over previous
//
#include <hip/hip_runtime.h>
#include <math.h>

typedef __attribute__((ext_vector_type(8))) short bf16x8;
typedef __attribute__((ext_vector_type(4))) float f32x4;

static inline size_t align256(size_t x) { return (x + 255) & ~(size_t)255; }

__device__ inline ushort f2bf(float f) {
    uint u = __float_as_uint(f);
    u = (u + 0x7fffu + ((u >> 16) & 1u)) >> 16;
    return (ushort)u;
}
__device__ inline float bf2f(ushort b) { return __uint_as_float(((uint)b) << 16); }

// ---- manual OCP e4m3fn encode/decode (self-consistent pair), |x| <= 1 ----
__device__ inline uint f2fp8(float x) {
    float ax = fabsf(x);
    uint s = (__float_as_uint(x) >> 31) << 7;
    if (ax < 0.015625f) {                      // denormal: below 2^-6
        int q = (int)rintf(ax * 512.f);        // 0..8
        if (q == 8) return s | 0x08u;          // rounds up to min normal
        return s | (uint)q;
    }
    uint u = __float_as_uint(ax);
    u += 0x7ffffu + ((u >> 20) & 1u);          // RNE to 3-bit mantissa
    int e8 = (int)(u >> 23) - 127;
    uint m = (u >> 20) & 7u;
    return s | ((uint)(e8 + 7) << 3) | m;
}
__device__ inline float fp8dec(uint b) {
    uint s = (b >> 7) & 1u, e = (b >> 3) & 0xfu, m = b & 7u;
    float dn = (float)(int)m * 0.001953125f;   // m * 2^-9
    float nf = __uint_as_float((s << 31) | ((e + 120u) << 23) | (m << 20));
    float dv = s ? -dn : dn;
    return e ? nf : dv;
}
__device__ inline float fp8dot16(uint4 qa, uint4 qb) {
    uint ua[4] = {qa.x, qa.y, qa.z, qa.w};
    uint ub[4] = {qb.x, qb.y, qb.z, qb.w};
    float s = 0.f;
    #pragma unroll
    for (int i = 0; i < 4; i++)
        #pragma unroll
        for (int j = 0; j < 4; j++)
            s += fp8dec((ua[i] >> (8 * j)) & 0xffu) * fp8dec((ub[i] >> (8 * j)) & 0xffu);
    return s;
}

__device__ inline void fma8(float* acc, uint4 q, float s) {
    acc[0] += s * bf2f((ushort)(q.x & 0xffff)); acc[1] += s * bf2f((ushort)(q.x >> 16));
    acc[2] += s * bf2f((ushort)(q.y & 0xffff)); acc[3] += s * bf2f((ushort)(q.y >> 16));
    acc[4] += s * bf2f((ushort)(q.z & 0xffff)); acc[5] += s * bf2f((ushort)(q.z >> 16));
    acc[6] += s * bf2f((ushort)(q.w & 0xffff)); acc[7] += s * bf2f((ushort)(q.w >> 16));
}

// ---------- prep: edge-count atomics + all weight conversions ----------
__global__ void prep_kernel(const int* __restrict__ e_col, int E, int* __restrict__ cnt,
                            const float* __restrict__ W1, const float* __restrict__ W2,
                            const float* __restrict__ Wy,
                            ushort* __restrict__ W1t, ushort* __restrict__ W2t,
                            ushort* __restrict__ WyTb, int H) {
    int i = blockIdx.x * blockDim.x + threadIdx.x;
    int HH = H * H;
    if (i < E) {
        atomicAdd(&cnt[e_col[i]], 1);
    } else if (i < E + HH) {
        int j = i - E; int k = j / H, n = j % H;
        W1t[(size_t)n * H + k] = f2bf(W1[j]);
    } else if (i < E + 2 * HH) {
        int j = i - E - HH; int k = j / H, n = j % H;
        W2t[(size_t)n * H + k] = f2bf(W2[j]);
    } else if (i < E + 2 * HH + 64 * H) {
        int j = i - E - 2 * HH; int n = j / H, k = j % H;
        WyTb[j] = (n < 40) ? f2bf(Wy[(size_t)k * 40 + n]) : (ushort)0;
    }
}

// ---------- scan + dinv ----------
__global__ void scan_offsets(const int* __restrict__ cnt, int* __restrict__ offsets,
                             int* __restrict__ fillpos, float* __restrict__ dinv, int N) {
    __shared__ int partial[256];
    __shared__ int base[257];
    int t = threadIdx.x;
    int chunk = (N + 255) / 256;
    int start = t * chunk;
    int end = min(start + chunk, N);
    int s = 0;
    for (int i = start; i < end; i++) s += cnt[i];
    partial[t] = s;
    __syncthreads();
    if (t == 0) {
        int acc = 0;
        for (int i = 0; i < 256; i++) { base[i] = acc; acc += partial[i]; }
        base[256] = acc;
    }
    __syncthreads();
    int acc = base[t];
    for (int i = start; i < end; i++) {
        offsets[i] = acc;
        fillpos[i] = acc;
        dinv[i] = rsqrtf((float)(cnt[i] + 1));
        acc += cnt[i];
    }
    if (t == 255) offsets[N] = base[256];
}

__global__ void fill_csr(const int* __restrict__ row, const int* __restrict__ col, int E,
                         int* __restrict__ fillpos, int* __restrict__ csr_src) {
    int e = blockIdx.x * blockDim.x + threadIdx.x;
    if (e < E) {
        int p = atomicAdd(&fillpos[col[e]], 1);
        csr_src[p] = row[e];
    }
}

// ---------- bf16 MFMA GEMM (A optionally f32, converted in staging) ----------
template<bool AF32>
__global__ __launch_bounds__(256) void gemm_bf16_kernel(const void* __restrict__ Av,
                                                        const ushort* __restrict__ Bt,
                                                        ushort* __restrict__ C, int M) {
    __shared__ ushort As[128][40];
    __shared__ ushort Bs[128][40];
    const int K = 256;
    int t = threadIdx.x;
    int lane = t & 63, w = t >> 6;
    int wm = w >> 1, wn = w & 1;
    int brow = blockIdx.y * 128, bcol = blockIdx.x * 128;
    int l15 = lane & 15, l4 = lane >> 4;

    f32x4 acc[4][4];
    for (int i = 0; i < 4; i++)
        for (int j = 0; j < 4; j++) {
            f32x4 z = {0.f, 0.f, 0.f, 0.f};
            acc[i][j] = z;
        }

    for (int k0 = 0; k0 < K; k0 += 32) {
        #pragma unroll
        for (int i = 0; i < 2; i++) {
            int idx = t + i * 256;
            int r = idx >> 2, seg = idx & 3;
            if constexpr (AF32) {
                const float* A = (const float*)Av;
                const float* ap = A + (size_t)(brow + r) * K + k0 + seg * 8;
                float4 f0 = *(const float4*)ap;
                float4 f1 = *(const float4*)(ap + 4);
                uint4 va;
                va.x = f2bf(f0.x) | ((uint)f2bf(f0.y) << 16);
                va.y = f2bf(f0.z) | ((uint)f2bf(f0.w) << 16);
                va.z = f2bf(f1.x) | ((uint)f2bf(f1.y) << 16);
                va.w = f2bf(f1.z) | ((uint)f2bf(f1.w) << 16);
                *(uint4*)&As[r][seg * 8] = va;
            } else {
                const ushort* A = (const ushort*)Av;
                *(uint4*)&As[r][seg * 8] = *(const uint4*)(A + (size_t)(brow + r) * K + k0 + seg * 8);
            }
            *(uint4*)&Bs[r][seg * 8] = *(const uint4*)(Bt + (size_t)(bcol + r) * K + k0 + seg * 8);
        }
        __syncthreads();

        bf16x8 af[4], bfr[4];
        #pragma unroll
        for (int mf = 0; mf < 4; mf++)
            af[mf] = *(const bf16x8*)&As[wm * 64 + mf * 16 + l15][l4 * 8];
        #pragma unroll
        for (int nf = 0; nf < 4; nf++)
            bfr[nf] = *(const bf16x8*)&Bs[wn * 64 + nf * 16 + l15][l4 * 8];

        #pragma unroll
        for (int mf = 0; mf < 4; mf++)
            #pragma unroll
            for (int nf = 0; nf < 4; nf++)
                acc[mf][nf] = __builtin_amdgcn_mfma_f32_16x16x32_bf16(af[mf], bfr[nf], acc[mf][nf], 0, 0, 0);
        __syncthreads();
    }

    #pragma unroll
    for (int mf = 0; mf < 4; mf++)
        #pragma unroll
        for (int nf = 0; nf < 4; nf++)
            #pragma unroll
            for (int j = 0; j < 4; j++) {
                int r = brow + wm * 64 + mf * 16 + l4 * 4 + j;
                int c = bcol + wn * 64 + nf * 16 + l15;
                C[(size_t)r * 256 + c] = f2bf(acc[mf][nf][j]);
            }
}

// ---------- agg pass1: 32 lanes/node, relu, bf16 out ----------
__global__ __launch_bounds__(256) void gcn_agg1_kernel(const ushort* __restrict__ xw,
                                                       const float* __restrict__ dinv,
                                                       const int* __restrict__ offsets,
                                                       const int* __restrict__ csr_src,
                                                       const float* __restrict__ bias,
                                                       ushort* __restrict__ out_b, int N) {
    int t = threadIdx.x;
    int v = (blockIdx.x * blockDim.x + t) >> 5;
    int l = t & 31;
    if (v >= N) return;
    float dv = dinv[v];
    float acc[8] = {0, 0, 0, 0, 0, 0, 0, 0};
    uint4 q = *(const uint4*)(xw + (size_t)v * 256 + l * 8);
    fma8(acc, q, dv * dv);
    int beg = offsets[v], end = offsets[v + 1];
    int e = beg;
    for (; e + 2 <= end; e += 2) {
        int r0 = csr_src[e], r1 = csr_src[e + 1];
        uint4 p0 = *(const uint4*)(xw + (size_t)r0 * 256 + l * 8);
        uint4 p1 = *(const uint4*)(xw + (size_t)r1 * 256 + l * 8);
        fma8(acc, p0, dinv[r0] * dv);
        fma8(acc, p1, dinv[r1] * dv);
    }
    if (e < end) {
        int r0 = csr_src[e];
        uint4 p0 = *(const uint4*)(xw + (size_t)r0 * 256 + l * 8);
        fma8(acc, p0, dinv[r0] * dv);
    }
    float4 b0 = *(const float4*)(bias + l * 8);
    float4 b1 = *(const float4*)(bias + l * 8 + 4);
    acc[0] = fmaxf(acc[0] + b0.x, 0.f); acc[1] = fmaxf(acc[1] + b0.y, 0.f);
    acc[2] = fmaxf(acc[2] + b0.z, 0.f); acc[3] = fmaxf(acc[3] + b0.w, 0.f);
    acc[4] = fmaxf(acc[4] + b1.x, 0.f); acc[5] = fmaxf(acc[5] + b1.y, 0.f);
    acc[6] = fmaxf(acc[6] + b1.z, 0.f); acc[7] = fmaxf(acc[7] + b1.w, 0.f);
    uint4 o;
    o.x = f2bf(acc[0]) | ((uint)f2bf(acc[1]) << 16);
    o.y = f2bf(acc[2]) | ((uint)f2bf(acc[3]) << 16);
    o.z = f2bf(acc[4]) | ((uint)f2bf(acc[5]) << 16);
    o.w = f2bf(acc[6]) | ((uint)f2bf(acc[7]) << 16);
    *(uint4*)(out_b + (size_t)v * 256 + l * 8) = o;
}

// ---------- agg pass2 + bias + double l2norm; writes rep f32, repb bf16, rep8 fp8 ----------
__global__ __launch_bounds__(256) void gcn_agg2_kernel(const ushort* __restrict__ xw,
                                                       const float* __restrict__ dinv,
                                                       const int* __restrict__ offsets,
                                                       const int* __restrict__ csr_src,
                                                       const float* __restrict__ b2,
                                                       float* __restrict__ rep,
                                                       ushort* __restrict__ repb,
                                                       unsigned char* __restrict__ rep8, int N) {
    int t = threadIdx.x;
    int v = (blockIdx.x * blockDim.x + t) >> 5;
    int l = t & 31;
    if (v >= N) return;
    float dv = dinv[v];
    float acc[8] = {0, 0, 0, 0, 0, 0, 0, 0};
    uint4 q = *(const uint4*)(xw + (size_t)v * 256 + l * 8);
    fma8(acc, q, dv * dv);
    int beg = offsets[v], end = offsets[v + 1];
    int e = beg;
    for (; e + 2 <= end; e += 2) {
        int r0 = csr_src[e], r1 = csr_src[e + 1];
        uint4 p0 = *(const uint4*)(xw + (size_t)r0 * 256 + l * 8);
        uint4 p1 = *(const uint4*)(xw + (size_t)r1 * 256 + l * 8);
        fma8(acc, p0, dinv[r0] * dv);
        fma8(acc, p1, dinv[r1] * dv);
    }
    if (e < end) {
        int r0 = csr_src[e];
        uint4 p0 = *(const uint4*)(xw + (size_t)r0 * 256 + l * 8);
        fma8(acc, p0, dinv[r0] * dv);
    }
    float4 b0 = *(const float4*)(b2 + l * 8);
    float4 b1 = *(const float4*)(b2 + l * 8 + 4);
    acc[0] += b0.x; acc[1] += b0.y; acc[2] += b0.z; acc[3] += b0.w;
    acc[4] += b1.x; acc[5] += b1.y; acc[6] += b1.z; acc[7] += b1.w;

    float ss = 0.f;
    #pragma unroll
    for (int i = 0; i < 8; i++) ss += acc[i] * acc[i];
    #pragma unroll
    for (int o = 1; o < 32; o <<= 1) ss += __shfl_xor(ss, o);
    float n1 = fmaxf(sqrtf(ss), 1e-12f);
    float i1 = 1.f / n1;
    float n2 = fmaxf(sqrtf(ss) * i1, 1e-12f);
    float sc = i1 / n2;
    #pragma unroll
    for (int i = 0; i < 8; i++) acc[i] *= sc;

    float4 o0, o1;
    o0.x = acc[0]; o0.y = acc[1]; o0.z = acc[2]; o0.w = acc[3];
    o1.x = acc[4]; o1.y = acc[5]; o1.z = acc[6]; o1.w = acc[7];
    *(float4*)(rep + (size_t)v * 256 + l * 8) = o0;
    *(float4*)(rep + (size_t)v * 256 + l * 8 + 4) = o1;
    uint4 ob;
    ob.x = f2bf(acc[0]) | ((uint)f2bf(acc[1]) << 16);
    ob.y = f2bf(acc[2]) | ((uint)f2bf(acc[3]) << 16);
    ob.z = f2bf(acc[4]) | ((uint)f2bf(acc[5]) << 16);
    ob.w = f2bf(acc[6]) | ((uint)f2bf(acc[7]) << 16);
    *(uint4*)(repb + (size_t)v * 256 + l * 8) = ob;
    uint2 o8;
    o8.x = f2fp8(acc[0]) | (f2fp8(acc[1]) << 8) | (f2fp8(acc[2]) << 16) | (f2fp8(acc[3]) << 24);
    o8.y = f2fp8(acc[4]) | (f2fp8(acc[5]) << 8) | (f2fp8(acc[6]) << 16) | (f2fp8(acc[7]) << 24);
    *(uint2*)(rep8 + (size_t)v * 256 + l * 8) = o8;
}

// ---------- y = repb @ WyTb^T + by (MFMA, 64x64 tile) ----------
__global__ __launch_bounds__(256) void gemm_y_kernel(const ushort* __restrict__ A,
                                                     const ushort* __restrict__ Bt,
                                                     const float* __restrict__ by,
                                                     float* __restrict__ y, int M) {
    __shared__ ushort As[64][40];
    __shared__ ushort Bs[64][40];
    const int K = 256;
    int t = threadIdx.x;
    int lane = t & 63, w = t >> 6;
    int brow = blockIdx.x * 64;
    int l15 = lane & 15, l4 = lane >> 4;
    f32x4 acc[4];
    for (int i = 0; i < 4; i++) { f32x4 z = {0.f, 0.f, 0.f, 0.f}; acc[i] = z; }
    for (int k0 = 0; k0 < K; k0 += 32) {
        int r = t >> 2, seg = t & 3;
        *(uint4*)&As[r][seg * 8] = *(const uint4*)(A + (size_t)(brow + r) * K + k0 + seg * 8);
        *(uint4*)&Bs[r][seg * 8] = *(const uint4*)(Bt + (size_t)r * K + k0 + seg * 8);
        __syncthreads();
        bf16x8 af = *(const bf16x8*)&As[w * 16 + l15][l4 * 8];
        #pragma unroll
        for (int nf = 0; nf < 4; nf++) {
            bf16x8 bfr = *(const bf16x8*)&Bs[nf * 16 + l15][l4 * 8];
            acc[nf] = __builtin_amdgcn_mfma_f32_16x16x32_bf16(af, bfr, acc[nf], 0, 0, 0);
        }
        __syncthreads();
    }
    #pragma unroll
    for (int nf = 0; nf < 4; nf++)
        #pragma unroll
        for (int j = 0; j < 4; j++) {
            int r = brow + w * 16 + l4 * 4 + j;
            int c = nf * 16 + l15;
            if (c < 40) y[(size_t)r * 40 + c] = acc[nf][j] + by[c];
        }
}

// ---------- loss: 16 lanes/edge, fp8 rows, contention-free reduction ----------
__global__ __launch_bounds__(256) void loss_edges_kernel(const unsigned char* __restrict__ rep8,
                                                         const int* __restrict__ pos_e,
                                                         const int* __restrict__ neg_e,
                                                         const float* __restrict__ sim,
                                                         const float* __restrict__ lsm,
                                                         float2* __restrict__ partials,
                                                         int E, int N) {
    int t = threadIdx.x;
    int l16 = t & 15;
    int g = (blockIdx.x * blockDim.x + t) >> 4;
    int ng = (gridDim.x * blockDim.x) >> 4;
    float tgt = lsm[0];
    float sse = 0.f, cntf = 0.f;
    for (int idx = g; idx < 2 * E; idx += ng) {
        bool is_pos = idx < E;
        int ei = is_pos ? idx : idx - E;
        const int* ep = is_pos ? pos_e : neg_e;
        int a = ep[ei];
        int b = ep[E + ei];
        if (a < b) {
            uint4 qa = *(const uint4*)(rep8 + (size_t)a * 256 + l16 * 16);
            uint4 qb = *(const uint4*)(rep8 + (size_t)b * 256 + l16 * 16);
            float d = fp8dot16(qa, qb);
            #pragma unroll
            for (int o = 1; o < 16; o <<= 1) d += __shfl_xor(d, o);
            float wr = fmaxf(d, 0.f);
            float term;
            if (is_pos) {
                float fsim = sim[(size_t)a * N + b];
                float p = fsim * 0.5f + wr * 0.5f;
                term = (p - tgt) * (p - tgt);
            } else {
                term = wr * wr;
            }
            sse += term;
            cntf += 1.f;
        }
    }
    sse += __shfl_xor(sse, 16); cntf += __shfl_xor(cntf, 16);
    sse += __shfl_xor(sse, 32); cntf += __shfl_xor(cntf, 32);
    __shared__ float s_sse[4], s_cnt[4];
    if ((t & 63) == 0) { s_sse[t >> 6] = sse; s_cnt[t >> 6] = cntf; }
    __syncthreads();
    if (t == 0) {
        float2 pp;
        pp.x = s_sse[0] + s_sse[1] + s_sse[2] + s_sse[3];
        pp.y = s_cnt[0] + s_cnt[1] + s_cnt[2] + s_cnt[3];
        partials[blockIdx.x] = pp;
    }
}

__global__ __launch_bounds__(256) void finalize_loss_kernel(const float2* __restrict__ partials,
                                                            int nb, float* __restrict__ out_loss,
                                                            int n) {
    __shared__ float s_sse[4], s_cnt[4];
    int t = threadIdx.x;
    float sse = 0.f, cnt = 0.f;
    for (int i = t; i < nb; i += 256) {
        float2 p = partials[i];
        sse += p.x; cnt += p.y;
    }
    #pragma unroll
    for (int o = 1; o < 64; o <<= 1) { sse += __shfl_xor(sse, o); cnt += __shfl_xor(cnt, o); }
    int w = t >> 6;
    if ((t & 63) == 0) { s_sse[w] = sse; s_cnt[w] = cnt; }
    __syncthreads();
    if (t == 0) {
        float S = s_sse[0] + s_sse[1] + s_sse[2] + s_sse[3];
        float Cc = s_cnt[0] + s_cnt[1] + s_cnt[2] + s_cnt[3];
        out_loss[0] = S * (float)n / Cc;
    }
}

extern "C" void kernel_launch(void* const* d_in, const int* in_sizes, int n_in,
                              void* d_out, int out_size, void* d_ws, size_t ws_size,
                              hipStream_t stream) {
    const int*   edge  = (const int*)d_in[0];
    const int*   nedge = (const int*)d_in[1];
    const float* feat  = (const float*)d_in[2];
    const float* sim   = (const float*)d_in[3];
    const float* lsm   = (const float*)d_in[4];
    const float* W1    = (const float*)d_in[5];
    const float* b1    = (const float*)d_in[6];
    const float* W2    = (const float*)d_in[7];
    const float* b2    = (const float*)d_in[8];
    const float* Wy    = (const float*)d_in[9];
    const float* by    = (const float*)d_in[10];

    const int E = in_sizes[0] / 2;
    const int H = in_sizes[6];           // 256
    const int F = in_sizes[5] / H;       // 256
    const int N = in_sizes[2] / F;       // 16384

    const int* e_row = edge;
    const int* e_col = edge + E;

    const int LOSS_BLOCKS = 2048;

    // workspace carve-up
    char* p = (char*)d_ws;
    int*    cnt      = (int*)p;    p += align256((size_t)N * 4);
    float*  dinv     = (float*)p;  p += align256((size_t)N * 4);
    int*    offsets  = (int*)p;    p += align256((size_t)(N + 1) * 4);
    int*    fillpos  = (int*)p;    p += align256((size_t)N * 4);
    int*    csr_src  = (int*)p;    p += align256((size_t)E * 4);
    ushort* W1t      = (ushort*)p; p += align256((size_t)F * H * 2);
    ushort* W2t      = (ushort*)p; p += align256((size_t)H * H * 2);
    ushort* WyTb     = (ushort*)p; p += align256((size_t)64 * H * 2);
    ushort* h1b      = (ushort*)p; p += align256((size_t)N * H * 2);
    ushort* xwb      = (ushort*)p; p += align256((size_t)N * H * 2);
    ushort* repb     = (ushort*)p; p += align256((size_t)N * H * 2);
    unsigned char* rep8 = (unsigned char*)p; p += align256((size_t)N * H);
    float2* partials = (float2*)p; p += align256((size_t)LOSS_BLOCKS * 8);

    float* rep  = (float*)d_out;
    float* loss = rep + (size_t)N * H;
    float* yout = loss + 1;

    hipMemsetAsync(cnt, 0, (size_t)N * 4, stream);

    // prep: count + all weight conversions
    {
        int total = E + 2 * H * H + 64 * H;
        prep_kernel<<<(total + 255) / 256, 256, 0, stream>>>(e_col, E, cnt, W1, W2, Wy,
                                                             W1t, W2t, WyTb, H);
    }
    scan_offsets<<<1, 256, 0, stream>>>(cnt, offsets, fillpos, dinv, N);
    fill_csr<<<(E + 255) / 256, 256, 0, stream>>>(e_row, e_col, E, fillpos, csr_src);

    // conv1: xwb = bf16(feat) @ W1
    {
        dim3 grid(2, N / 128);
        gemm_bf16_kernel<true><<<grid, 256, 0, stream>>>((const void*)feat, W1t, xwb, N);
    }
    gcn_agg1_kernel<<<N * 32 / 256, 256, 0, stream>>>(xwb, dinv, offsets, csr_src, b1, h1b, N);

    // conv2
    {
        dim3 grid(2, N / 128);
        gemm_bf16_kernel<false><<<grid, 256, 0, stream>>>((const void*)h1b, W2t, xwb, N);
    }
    gcn_agg2_kernel<<<N * 32 / 256, 256, 0, stream>>>(xwb, dinv, offsets, csr_src, b2,
                                                      rep, repb, rep8, N);

    // y head
    gemm_y_kernel<<<N / 64, 256, 0, stream>>>(repb, WyTb, by, yout, N);

    // loss
    loss_edges_kernel<<<LOSS_BLOCKS, 256, 0, stream>>>(rep8, edge, nedge, sim, lsm,
                                                       partials, E, N);
    finalize_loss_kernel<<<1, 256, 0, stream>>>(partials, LOSS_BLOCKS, loss, N);
}